// Round 4
// baseline (190.676 us; speedup 1.0000x reference)
//
#include <hip/hip_runtime.h>
#include <math.h>

#define B 2
#define T 512
#define C 512
#define H 64

// scale = C^-0.5 = 1/sqrt(512)
#define SCALE 0.044194173824159216f

static __device__ __forceinline__ float qnan() { return __builtin_nanf(""); }

// ---------------------------------------------------------------------------
// Kernel 1: token scans + per-batch pitch histogram + time RLE.
// One wave per batch.
// Outputs: prop_t[b][i], prop_p[b][i],
//          cntP[b][129]   (pitch histogram of shifted prop_p, valid only)
//          tval[b][0..L)  (distinct time values, monotone runs)
//          tcnt[b][0..L)  (run lengths)
//          meta[b] = {L, nanT, nanP, pad}
// ---------------------------------------------------------------------------
__global__ __launch_bounds__(64) void scan_kernel(const int* __restrict__ tok,
                                                  float* __restrict__ prop_t,
                                                  float* __restrict__ prop_p,
                                                  int* __restrict__ cntP,
                                                  int* __restrict__ meta,
                                                  float* __restrict__ tval,
                                                  int* __restrict__ tcnt) {
    int b = blockIdx.x;
    int lane = threadIdx.x;
    const int* tb = tok + b * T;

    __shared__ int tks[T];
    __shared__ float ptv[T];   // prop_t values
    __shared__ float ff[T];    // unshifted pitch values
    __shared__ int hist[129];
    __shared__ int cnts[520];
    __shared__ int nanPc;

    for (int i = lane; i < T; i += 64) tks[i] = tb[i];
    for (int i = lane; i < 520; i += 64) cnts[i] = 0;
    for (int i = lane; i < 129; i += 64) hist[i] = 0;
    if (lane == 0) nanPc = 0;
    __syncthreads();

    const int p0 = lane * 8;
    unsigned long long lowmask = lane ? ((1ull << lane) - 1ull) : 0ull;

    // ---- time scan ----
    {
        float lsum[8];
        bool lflag[8];
        float s = 0.f;
        bool f = false;
#pragma unroll
        for (int i = 0; i < 8; ++i) {
            int tk = tks[p0 + i];
            if (tk >= 288) { s += (float)(tk - 288); f = true; }
            lsum[i] = s;
            lflag[i] = f;
        }
        float inc = s;
#pragma unroll
        for (int off = 1; off < 64; off <<= 1) {
            float o = __shfl_up(inc, off);
            if (lane >= off) inc += o;
        }
        float ex = inc - s;
        unsigned long long fmask = __ballot(f);
        bool exf = (fmask & lowmask) != 0ull;
#pragma unroll
        for (int i = 0; i < 8; ++i) {
            bool have = exf | lflag[i];
            float outv = have ? rintf((ex + lsum[i] + 1.0f) / 10.0f) : qnan();
            prop_t[b * T + p0 + i] = outv;
            ptv[p0 + i] = outv;
        }
    }

    // ---- pitch scan (copy-last-valid) ----
    {
        float lval[8];
        bool lvalid[8];
        float cv = 0.f;
        bool cvd = false;
#pragma unroll
        for (int i = 0; i < 8; ++i) {
            int tk = tks[p0 + i];
            if (tk < 256) {
                cv = (float)((tk >= 128 ? tk - 128 : tk) + 1);
                cvd = true;
            }
            lval[i] = cv;
            lvalid[i] = cvd;
        }
        unsigned long long vmask = __ballot(cvd);
        unsigned long long lower = vmask & lowmask;
        bool exvd = lower != 0ull;
        int src = 63 - __clzll(lower | 1ull);
        float exv = __shfl(cv, src);
#pragma unroll
        for (int i = 0; i < 8; ++i) {
            bool hv = exvd | lvalid[i];
            float fv = lvalid[i] ? lval[i] : exv;
            ff[p0 + i] = hv ? fv : qnan();
        }
    }
    __syncthreads();

    // ---- shifted pitch write + histogram ----
    for (int i = lane; i < T; i += 64) {
        float v = ff[min(i + 1, T - 1)];
        prop_p[b * T + i] = v;
        if (v == v) atomicAdd(&hist[(int)v - 1], 1);
        else atomicAdd(&nanPc, 1);
    }

    // ---- time RLE ----
    int lstart[8];
    int lcnt = 0, lnan = 0;
#pragma unroll
    for (int u = 0; u < 8; ++u) {
        int i = p0 + u;
        float cur = ptv[i];
        bool val = (cur == cur);
        bool st = false;
        if (val) {
            if (i == 0) st = true;
            else {
                float pv = ptv[i - 1];
                st = !(pv == pv) || (pv != cur);
            }
        } else lnan++;
        lstart[u] = st;
        lcnt += st;
    }
    int incs = lcnt;
#pragma unroll
    for (int off = 1; off < 64; off <<= 1) {
        int o = __shfl_up(incs, off);
        if (lane >= off) incs += o;
    }
    int base = incs - lcnt;
    int Lruns = __shfl(incs, 63);
    int tn = lnan;
#pragma unroll
    for (int off = 32; off; off >>= 1) tn += __shfl_down(tn, off);
    tn = __shfl(tn, 0);

    int s2 = base;
#pragma unroll
    for (int u = 0; u < 8; ++u) {
        int i = p0 + u;
        float cur = ptv[i];
        if (lstart[u]) { tval[b * 520 + s2] = cur; s2++; }
        if (cur == cur) atomicAdd(&cnts[s2 - 1], 1);
    }
    __syncthreads();

    for (int i = lane; i < Lruns; i += 64) tcnt[b * 520 + i] = cnts[i];
    for (int i = lane; i < 129; i += 64) cntP[b * 129 + i] = hist[i];
    if (lane == 0) {
        meta[b * 4] = Lruns;
        meta[b * 4 + 1] = tn;
        meta[b * 4 + 2] = nanPc;
    }
}

// ---------------------------------------------------------------------------
// Kernel 2: q/k/v projections. 256 threads; 4 rows/block; K-split across
// waves (128 k each, 12 fma per 3 W-loads), LDS reduce across waves.
// ---------------------------------------------------------------------------
__global__ __launch_bounds__(256) void qkv_kernel(const float* __restrict__ x,
                                                  const float* __restrict__ Wq,
                                                  const float* __restrict__ Wk,
                                                  const float* __restrict__ Wv,
                                                  float* __restrict__ q,
                                                  float* __restrict__ k,
                                                  float* __restrict__ v) {
    int r0 = blockIdx.x * 4;
    int tid = threadIdx.x;
    int wave = tid >> 6;
    int c = tid & 63;

    __shared__ float xs[4 * C];
    __shared__ float red2[4 * 4 * 64];  // [wave][row][c]

    const float4* xv4 = (const float4*)(x + (size_t)r0 * C);
    float4* xs4 = (float4*)xs;
    xs4[tid] = xv4[tid];
    xs4[tid + 256] = xv4[tid + 256];
    __syncthreads();

    float aq[4] = {0, 0, 0, 0}, ak[4] = {0, 0, 0, 0}, av[4] = {0, 0, 0, 0};
    int kk0 = wave * 128;
#pragma unroll 4
    for (int u = 0; u < 128; ++u) {
        int kk = kk0 + u;
        float wq = Wq[kk * H + c];
        float wk = Wk[kk * H + c];
        float wv = Wv[kk * H + c];
#pragma unroll
        for (int r = 0; r < 4; ++r) {
            float xv = xs[r * C + kk];
            aq[r] = fmaf(xv, wq, aq[r]);
            ak[r] = fmaf(xv, wk, ak[r]);
            av[r] = fmaf(xv, wv, av[r]);
        }
    }

    int rr = tid >> 6;  // row this thread reduces
    // q
#pragma unroll
    for (int r = 0; r < 4; ++r) red2[(wave * 4 + r) * 64 + c] = aq[r];
    __syncthreads();
    {
        float s = red2[(0 + rr) * 64 + c] + red2[(4 + rr) * 64 + c] +
                  red2[(8 + rr) * 64 + c] + red2[(12 + rr) * 64 + c];
        q[(size_t)(r0 + rr) * H + c] = s;
    }
    __syncthreads();
    // k
#pragma unroll
    for (int r = 0; r < 4; ++r) red2[(wave * 4 + r) * 64 + c] = ak[r];
    __syncthreads();
    {
        float s = red2[(0 + rr) * 64 + c] + red2[(4 + rr) * 64 + c] +
                  red2[(8 + rr) * 64 + c] + red2[(12 + rr) * 64 + c];
        k[(size_t)(r0 + rr) * H + c] = s;
    }
    __syncthreads();
    // v
#pragma unroll
    for (int r = 0; r < 4; ++r) red2[(wave * 4 + r) * 64 + c] = av[r];
    __syncthreads();
    {
        float s = red2[(0 + rr) * 64 + c] + red2[(4 + rr) * 64 + c] +
                  red2[(8 + rr) * 64 + c] + red2[(12 + rr) * 64 + c];
        v[(size_t)(r0 + rr) * H + c] = s;
    }
}

// ---------------------------------------------------------------------------
// Kernel 3: relative-embedding sums via histogram/RLE entries.
// Block = (b,j), 256 threads. Entry list: 129 pitch bins + nanP entry +
// L time runs + nanT entry. Entries strided across waves (wave-uniform e ->
// coalesced row gathers). Pos term via closed-form window.
// k' = scale*k + Rk, v' = v + Rv.
// ---------------------------------------------------------------------------
__global__ __launch_bounds__(256) void relsum_kernel(
    const float* __restrict__ prop_t, const float* __restrict__ prop_p,
    const int* __restrict__ cntP, const int* __restrict__ meta,
    const float* __restrict__ tval, const int* __restrict__ tcnt,
    const float* __restrict__ Ek_pos, const float* __restrict__ Ev_pos,
    const float* __restrict__ Ek_time, const float* __restrict__ Ev_time,
    const float* __restrict__ Ek_pitch, const float* __restrict__ Ev_pitch,
    float* __restrict__ k, float* __restrict__ v) {
    int b = blockIdx.x >> 9;
    int j = blockIdx.x & 511;
    int tid = threadIdx.x;
    int wave = tid >> 6;
    int c = tid & 63;

    __shared__ float tvL[520];
    __shared__ int tcL[520];
    __shared__ int cpL[129];
    __shared__ float redK[256];
    __shared__ float redV[256];

    int L = meta[b * 4];
    int nanT = meta[b * 4 + 1];
    int nanP = meta[b * 4 + 2];
    for (int i = tid; i < L; i += 256) {
        tvL[i] = tval[b * 520 + i];
        tcL[i] = tcnt[b * 520 + i];
    }
    if (tid < 129) cpL[tid] = cntP[b * 129 + tid];
    __syncthreads();

    float pjt = prop_t[b * T + j];
    float pjp = prop_p[b * T + j];

    float aK = 0.f, aV = 0.f;

    // ---- pitch + time entries (wave-uniform e) ----
    int NE = 130 + L + 1;
    for (int e = wave; e < NE; e += 4) {
        int idx, cnt;
        const float* EK;
        const float* EV;
        if (e < 130) {
            EK = Ek_pitch; EV = Ev_pitch;
            if (e == 129) { idx = 0; cnt = nanP; }
            else {
                cnt = cpL[e];
                float dv = pjp - (float)(e + 1);  // in [-128,128] when valid
                idx = (dv != dv) ? 0 : (int)dv + 128;
            }
        } else {
            EK = Ek_time; EV = Ev_time;
            int r = e - 130;
            if (r == L) { idx = 0; cnt = nanT; }
            else {
                cnt = tcL[r];
                float dt = pjt - tvL[r];
                idx = (dt != dt) ? 0 : (int)fminf(fmaxf(dt, -200.f), 200.f) + 200;
            }
        }
        if (cnt) {
            float fc = (float)cnt;
            aK = fmaf(fc, EK[idx * H + c], aK);
            aV = fmaf(fc, EV[idx * H + c], aV);
        }
    }

    // ---- pos term: window [lo,hi] once each + edge multiplicities ----
    int lo = max(-25, j - (T - 1));
    int hi = min(25, j);
    for (int d = lo + wave; d <= hi; d += 4) {
        aK += Ek_pos[(d + 25) * H + c];
        aV += Ev_pos[(d + 25) * H + c];
    }
    if (wave == 0) {
        float c50 = (float)max(j - 25, 0);
        float c0 = (float)max((T - 26) - j, 0);
        aK = fmaf(c50, Ek_pos[50 * H + c], aK);
        aK = fmaf(c0, Ek_pos[0 * H + c], aK);
        aV = fmaf(c50, Ev_pos[50 * H + c], aV);
        aV = fmaf(c0, Ev_pos[0 * H + c], aV);
    }

    redK[tid] = aK;
    redV[tid] = aV;
    __syncthreads();

    if (tid < 64) {
        float sK = redK[tid] + redK[64 + tid] + redK[128 + tid] + redK[192 + tid];
        float sV = redV[tid] + redV[64 + tid] + redV[128 + tid] + redV[192 + tid];
        size_t o = (size_t)blockIdx.x * H + tid;
        k[o] = SCALE * k[o] + sK;
        v[o] = v[o] + sV;
    }
}

// ---------------------------------------------------------------------------
// Kernel 4: causal attention, tail-balanced pairing: block handles rows
// tl and th=511-tl of batch b (constant 513 score rows per block).
// k-tiles loaded once serve both q-rows; PV v-loads shared.
// ---------------------------------------------------------------------------
__global__ __launch_bounds__(256) void attn_kernel(const float* __restrict__ q,
                                                   const float* __restrict__ kp,
                                                   const float* __restrict__ vp,
                                                   float* __restrict__ out) {
    int b = blockIdx.x >> 8;
    int tl = blockIdx.x & 255;
    int th = (T - 1) - tl;
    int tid = threadIdx.x;
    int wave = tid >> 6;
    int lane = tid & 63;

    __shared__ float qsl[64], qsh[64];
    __shared__ float scl[256];
    __shared__ float sch[512];
    __shared__ float ktile[64 * 65];
    __shared__ float redH[256], redL[256];
    __shared__ float m4[4], s4[4];

    if (tid < 64) qsl[tid] = q[((size_t)b * T + tl) * H + tid];
    else if (tid < 128) qsh[tid - 64] = q[((size_t)b * T + th) * H + (tid - 64)];
    __syncthreads();

    int nsl = tl + 1;
    int nsh = th + 1;
    const float* kbase = kp + (size_t)b * T * H;
    const float* vbase = vp + (size_t)b * T * H;
    int c0 = wave * 16;

    for (int s0 = 0; s0 < nsh; s0 += 64) {
        int tile = min(64, nsh - s0);
        for (int f = tid; f < tile * 64; f += 256) {
            int r = f >> 6, cc = f & 63;
            ktile[r * 65 + cc] = kbase[(size_t)(s0 + r) * H + cc];
        }
        __syncthreads();
        float ph = 0.f, pl = 0.f;
        if (lane < tile) {
            const float* kr = &ktile[lane * 65 + c0];
#pragma unroll
            for (int i = 0; i < 16; ++i) ph = fmaf(qsh[c0 + i], kr[i], ph);
            if (s0 + lane < nsl) {
#pragma unroll
                for (int i = 0; i < 16; ++i) pl = fmaf(qsl[c0 + i], kr[i], pl);
            }
        }
        redH[wave * 64 + lane] = ph;
        redL[wave * 64 + lane] = pl;
        __syncthreads();
        if (tid < tile) {
            sch[s0 + tid] = redH[tid] + redH[64 + tid] + redH[128 + tid] + redH[192 + tid];
            if (s0 + tid < nsl)
                scl[s0 + tid] = redL[tid] + redL[64 + tid] + redL[128 + tid] + redL[192 + tid];
        }
        __syncthreads();
    }

    // ---- softmax row h ----
    float m = -INFINITY;
    for (int s = tid; s < nsh; s += 256) m = fmaxf(m, sch[s]);
#pragma unroll
    for (int off = 32; off; off >>= 1) m = fmaxf(m, __shfl_down(m, off));
    if (lane == 0) m4[wave] = m;
    __syncthreads();
    float mh = fmaxf(fmaxf(m4[0], m4[1]), fmaxf(m4[2], m4[3]));
    __syncthreads();
    // ---- softmax row l max ----
    m = -INFINITY;
    for (int s = tid; s < nsl; s += 256) m = fmaxf(m, scl[s]);
#pragma unroll
    for (int off = 32; off; off >>= 1) m = fmaxf(m, __shfl_down(m, off));
    if (lane == 0) m4[wave] = m;
    __syncthreads();
    float ml = fmaxf(fmaxf(m4[0], m4[1]), fmaxf(m4[2], m4[3]));

    // ---- exp + sums ----
    float ls = 0.f;
    for (int s = tid; s < nsh; s += 256) {
        float e = __expf(sch[s] - mh);
        sch[s] = e;
        ls += e;
    }
#pragma unroll
    for (int off = 32; off; off >>= 1) ls += __shfl_down(ls, off);
    if (lane == 0) s4[wave] = ls;
    __syncthreads();
    float sumh = s4[0] + s4[1] + s4[2] + s4[3];
    __syncthreads();
    ls = 0.f;
    for (int s = tid; s < nsl; s += 256) {
        float e = __expf(scl[s] - ml);
        scl[s] = e;
        ls += e;
    }
#pragma unroll
    for (int off = 32; off; off >>= 1) ls += __shfl_down(ls, off);
    if (lane == 0) s4[wave] = ls;
    __syncthreads();
    float suml = s4[0] + s4[1] + s4[2] + s4[3];

    // ---- PV (shared v loads) ----
    float ah = 0.f, al = 0.f;
    for (int s = wave; s < nsh; s += 4) {
        float vv = vbase[(size_t)s * H + lane];
        ah = fmaf(sch[s], vv, ah);
        if (s < nsl) al = fmaf(scl[s], vv, al);
    }
    redH[tid] = ah;
    redL[tid] = al;
    __syncthreads();

    if (tid < 64) {
        float oh = (redH[tid] + redH[64 + tid] + redH[128 + tid] + redH[192 + tid]) / sumh;
        out[((size_t)b * T + th) * H + tid] = oh;
        float ol = (redL[tid] + redL[64 + tid] + redL[128 + tid] + redL[192 + tid]) / suml;
        out[((size_t)b * T + tl) * H + tid] = ol;
    }
}

// ---------------------------------------------------------------------------
extern "C" void kernel_launch(void* const* d_in, const int* in_sizes, int n_in,
                              void* d_out, int out_size, void* d_ws, size_t ws_size,
                              hipStream_t stream) {
    const float* x        = (const float*)d_in[0];
    const int*   tok      = (const int*)d_in[1];
    const float* Wk       = (const float*)d_in[2];
    const float* Wq       = (const float*)d_in[3];
    const float* Wv       = (const float*)d_in[4];
    const float* Ek_pos   = (const float*)d_in[5];
    const float* Ev_pos   = (const float*)d_in[6];
    const float* Ek_time  = (const float*)d_in[7];
    const float* Ev_time  = (const float*)d_in[8];
    const float* Ek_pitch = (const float*)d_in[9];
    const float* Ev_pitch = (const float*)d_in[10];
    float* out = (float*)d_out;

    float* ws = (float*)d_ws;
    float* q      = ws;                        // B*T*H
    float* k      = q + B * T * H;             // B*T*H (becomes k')
    float* v      = k + B * T * H;             // B*T*H (becomes v')
    float* prop_t = v + B * T * H;             // B*T
    float* prop_p = prop_t + B * T;            // B*T
    int*   cntP   = (int*)(prop_p + B * T);    // B*129
    int*   meta   = cntP + B * 129;            // B*4
    float* tval   = (float*)(meta + B * 4);    // B*520
    int*   tcnt   = (int*)(tval + B * 520);    // B*520

    scan_kernel<<<B, 64, 0, stream>>>(tok, prop_t, prop_p, cntP, meta, tval, tcnt);
    qkv_kernel<<<B * T / 4, 256, 0, stream>>>(x, Wq, Wk, Wv, q, k, v);
    relsum_kernel<<<B * T, 256, 0, stream>>>(prop_t, prop_p, cntP, meta, tval, tcnt,
                                             Ek_pos, Ev_pos, Ek_time, Ev_time,
                                             Ek_pitch, Ev_pitch, k, v);
    attn_kernel<<<B * 256, 256, 0, stream>>>(q, k, v, out);
}

// Round 5
// 160.849 us; speedup vs baseline: 1.1854x; 1.1854x over previous
//
#include <hip/hip_runtime.h>
#include <math.h>

#define B 2
#define T 512
#define C 512
#define H 64

// scale = C^-0.5 = 1/sqrt(512)
#define SCALE 0.044194173824159216f

static __device__ __forceinline__ float qnan() { return __builtin_nanf(""); }

// ---------------------------------------------------------------------------
// Kernel 1: token scans + per-batch pitch histogram + time RLE.
// One wave per batch. (unchanged from R3)
// ---------------------------------------------------------------------------
__global__ __launch_bounds__(64) void scan_kernel(const int* __restrict__ tok,
                                                  float* __restrict__ prop_t,
                                                  float* __restrict__ prop_p,
                                                  int* __restrict__ cntP,
                                                  int* __restrict__ meta,
                                                  float* __restrict__ tval,
                                                  int* __restrict__ tcnt) {
    int b = blockIdx.x;
    int lane = threadIdx.x;
    const int* tb = tok + b * T;

    __shared__ int tks[T];
    __shared__ float ptv[T];
    __shared__ float ff[T];
    __shared__ int hist[129];
    __shared__ int cnts[520];
    __shared__ int nanPc;

    for (int i = lane; i < T; i += 64) tks[i] = tb[i];
    for (int i = lane; i < 520; i += 64) cnts[i] = 0;
    for (int i = lane; i < 129; i += 64) hist[i] = 0;
    if (lane == 0) nanPc = 0;
    __syncthreads();

    const int p0 = lane * 8;
    unsigned long long lowmask = lane ? ((1ull << lane) - 1ull) : 0ull;

    // ---- time scan ----
    {
        float lsum[8];
        bool lflag[8];
        float s = 0.f;
        bool f = false;
#pragma unroll
        for (int i = 0; i < 8; ++i) {
            int tk = tks[p0 + i];
            if (tk >= 288) { s += (float)(tk - 288); f = true; }
            lsum[i] = s;
            lflag[i] = f;
        }
        float inc = s;
#pragma unroll
        for (int off = 1; off < 64; off <<= 1) {
            float o = __shfl_up(inc, off);
            if (lane >= off) inc += o;
        }
        float ex = inc - s;
        unsigned long long fmask = __ballot(f);
        bool exf = (fmask & lowmask) != 0ull;
#pragma unroll
        for (int i = 0; i < 8; ++i) {
            bool have = exf | lflag[i];
            float outv = have ? rintf((ex + lsum[i] + 1.0f) / 10.0f) : qnan();
            prop_t[b * T + p0 + i] = outv;
            ptv[p0 + i] = outv;
        }
    }

    // ---- pitch scan (copy-last-valid) ----
    {
        float lval[8];
        bool lvalid[8];
        float cv = 0.f;
        bool cvd = false;
#pragma unroll
        for (int i = 0; i < 8; ++i) {
            int tk = tks[p0 + i];
            if (tk < 256) {
                cv = (float)((tk >= 128 ? tk - 128 : tk) + 1);
                cvd = true;
            }
            lval[i] = cv;
            lvalid[i] = cvd;
        }
        unsigned long long vmask = __ballot(cvd);
        unsigned long long lower = vmask & lowmask;
        bool exvd = lower != 0ull;
        int src = 63 - __clzll(lower | 1ull);
        float exv = __shfl(cv, src);
#pragma unroll
        for (int i = 0; i < 8; ++i) {
            bool hv = exvd | lvalid[i];
            float fv = lvalid[i] ? lval[i] : exv;
            ff[p0 + i] = hv ? fv : qnan();
        }
    }
    __syncthreads();

    for (int i = lane; i < T; i += 64) {
        float v = ff[min(i + 1, T - 1)];
        prop_p[b * T + i] = v;
        if (v == v) atomicAdd(&hist[(int)v - 1], 1);
        else atomicAdd(&nanPc, 1);
    }

    // ---- time RLE ----
    int lstart[8];
    int lcnt = 0, lnan = 0;
#pragma unroll
    for (int u = 0; u < 8; ++u) {
        int i = p0 + u;
        float cur = ptv[i];
        bool val = (cur == cur);
        bool st = false;
        if (val) {
            if (i == 0) st = true;
            else {
                float pv = ptv[i - 1];
                st = !(pv == pv) || (pv != cur);
            }
        } else lnan++;
        lstart[u] = st;
        lcnt += st;
    }
    int incs = lcnt;
#pragma unroll
    for (int off = 1; off < 64; off <<= 1) {
        int o = __shfl_up(incs, off);
        if (lane >= off) incs += o;
    }
    int base = incs - lcnt;
    int Lruns = __shfl(incs, 63);
    int tn = lnan;
#pragma unroll
    for (int off = 32; off; off >>= 1) tn += __shfl_down(tn, off);
    tn = __shfl(tn, 0);

    int s2 = base;
#pragma unroll
    for (int u = 0; u < 8; ++u) {
        int i = p0 + u;
        float cur = ptv[i];
        if (lstart[u]) { tval[b * 520 + s2] = cur; s2++; }
        if (cur == cur) atomicAdd(&cnts[s2 - 1], 1);
    }
    __syncthreads();

    for (int i = lane; i < Lruns; i += 64) tcnt[b * 520 + i] = cnts[i];
    for (int i = lane; i < 129; i += 64) cntP[b * 129 + i] = hist[i];
    if (lane == 0) {
        meta[b * 4] = Lruns;
        meta[b * 4 + 1] = tn;
        meta[b * 4 + 2] = nanPc;
    }
}

// ---------------------------------------------------------------------------
// Kernel 2: q/k/v projection, matrix-split. Block = (4-row group, matrix m).
// Wave w computes row rg*4+w of output m. Lane = (g = kk%4 group, c4 = col
// quad): streams 128 independent float4 W loads (full coalesced W rows),
// acc float4, fold g-groups via shfl_xor(16,32), lanes g==0 store float4.
// ---------------------------------------------------------------------------
__global__ __launch_bounds__(256) void qkv_kernel(const float* __restrict__ x,
                                                  const float* __restrict__ Wq,
                                                  const float* __restrict__ Wk,
                                                  const float* __restrict__ Wv,
                                                  float* __restrict__ q,
                                                  float* __restrict__ k,
                                                  float* __restrict__ v) {
    int rg = blockIdx.x & 255;           // row group (4 rows)
    int m = blockIdx.x >> 8;             // 0=q, 1=k, 2=v
    int tid = threadIdx.x;
    int wave = tid >> 6;
    int lane = tid & 63;
    int g = lane >> 4;                   // kk % 4 group
    int c4 = lane & 15;                  // float4 column index

    const float* Wm = (m == 0) ? Wq : ((m == 1) ? Wk : Wv);
    float* Om = (m == 0) ? q : ((m == 1) ? k : v);

    __shared__ float xs[4 * C];
    const float4* xv4 = (const float4*)(x + (size_t)rg * 4 * C);
    float4* xs4 = (float4*)xs;
    xs4[tid] = xv4[tid];
    xs4[tid + 256] = xv4[tid + 256];
    __syncthreads();

    const float4* W4 = (const float4*)Wm;   // [512][16] float4
    const float* xr = xs + wave * C;

    float4 acc = make_float4(0.f, 0.f, 0.f, 0.f);
#pragma unroll 8
    for (int u = 0; u < 128; ++u) {
        int kk = u * 4 + g;
        float4 w4 = W4[kk * 16 + c4];
        float xv = xr[kk];
        acc.x = fmaf(xv, w4.x, acc.x);
        acc.y = fmaf(xv, w4.y, acc.y);
        acc.z = fmaf(xv, w4.z, acc.z);
        acc.w = fmaf(xv, w4.w, acc.w);
    }

    // fold the 4 kk-groups (lanes differing in bits 4,5)
#pragma unroll
    for (int mask = 16; mask <= 32; mask <<= 1) {
        acc.x += __shfl_xor(acc.x, mask);
        acc.y += __shfl_xor(acc.y, mask);
        acc.z += __shfl_xor(acc.z, mask);
        acc.w += __shfl_xor(acc.w, mask);
    }

    if (g == 0) {
        float4* orow = (float4*)(Om + (size_t)(rg * 4 + wave) * H);
        orow[c4] = acc;
    }
}

// ---------------------------------------------------------------------------
// Kernel 3: relative-embedding sums via histogram/RLE entries (R3).
// k' = scale*k + Rk, v' = v + Rv.
// ---------------------------------------------------------------------------
__global__ __launch_bounds__(256) void relsum_kernel(
    const float* __restrict__ prop_t, const float* __restrict__ prop_p,
    const int* __restrict__ cntP, const int* __restrict__ meta,
    const float* __restrict__ tval, const int* __restrict__ tcnt,
    const float* __restrict__ Ek_pos, const float* __restrict__ Ev_pos,
    const float* __restrict__ Ek_time, const float* __restrict__ Ev_time,
    const float* __restrict__ Ek_pitch, const float* __restrict__ Ev_pitch,
    float* __restrict__ k, float* __restrict__ v) {
    int b = blockIdx.x >> 9;
    int j = blockIdx.x & 511;
    int tid = threadIdx.x;
    int wave = tid >> 6;
    int c = tid & 63;

    __shared__ float tvL[520];
    __shared__ int tcL[520];
    __shared__ int cpL[129];
    __shared__ float redK[256];
    __shared__ float redV[256];

    int L = meta[b * 4];
    int nanT = meta[b * 4 + 1];
    int nanP = meta[b * 4 + 2];
    for (int i = tid; i < L; i += 256) {
        tvL[i] = tval[b * 520 + i];
        tcL[i] = tcnt[b * 520 + i];
    }
    if (tid < 129) cpL[tid] = cntP[b * 129 + tid];
    __syncthreads();

    float pjt = prop_t[b * T + j];
    float pjp = prop_p[b * T + j];

    float aK = 0.f, aV = 0.f;

    int NE = 130 + L + 1;
    for (int e = wave; e < NE; e += 4) {
        int idx, cnt;
        const float* EK;
        const float* EV;
        if (e < 130) {
            EK = Ek_pitch; EV = Ev_pitch;
            if (e == 129) { idx = 0; cnt = nanP; }
            else {
                cnt = cpL[e];
                float dv = pjp - (float)(e + 1);
                idx = (dv != dv) ? 0 : (int)dv + 128;
            }
        } else {
            EK = Ek_time; EV = Ev_time;
            int r = e - 130;
            if (r == L) { idx = 0; cnt = nanT; }
            else {
                cnt = tcL[r];
                float dt = pjt - tvL[r];
                idx = (dt != dt) ? 0 : (int)fminf(fmaxf(dt, -200.f), 200.f) + 200;
            }
        }
        if (cnt) {
            float fc = (float)cnt;
            aK = fmaf(fc, EK[idx * H + c], aK);
            aV = fmaf(fc, EV[idx * H + c], aV);
        }
    }

    int lo = max(-25, j - (T - 1));
    int hi = min(25, j);
    for (int d = lo + wave; d <= hi; d += 4) {
        aK += Ek_pos[(d + 25) * H + c];
        aV += Ev_pos[(d + 25) * H + c];
    }
    if (wave == 0) {
        float c50 = (float)max(j - 25, 0);
        float c0 = (float)max((T - 26) - j, 0);
        aK = fmaf(c50, Ek_pos[50 * H + c], aK);
        aK = fmaf(c0, Ek_pos[0 * H + c], aK);
        aV = fmaf(c50, Ev_pos[50 * H + c], aV);
        aV = fmaf(c0, Ev_pos[0 * H + c], aV);
    }

    redK[tid] = aK;
    redV[tid] = aV;
    __syncthreads();

    if (tid < 64) {
        float sK = redK[tid] + redK[64 + tid] + redK[128 + tid] + redK[192 + tid];
        float sV = redV[tid] + redV[64 + tid] + redV[128 + tid] + redV[192 + tid];
        size_t o = (size_t)blockIdx.x * H + tid;
        k[o] = SCALE * k[o] + sK;
        v[o] = v[o] + sV;
    }
}

// ---------------------------------------------------------------------------
// Kernel 4: causal attention, tail-balanced pairing (R3).
// ---------------------------------------------------------------------------
__global__ __launch_bounds__(256) void attn_kernel(const float* __restrict__ q,
                                                   const float* __restrict__ kp,
                                                   const float* __restrict__ vp,
                                                   float* __restrict__ out) {
    int b = blockIdx.x >> 8;
    int tl = blockIdx.x & 255;
    int th = (T - 1) - tl;
    int tid = threadIdx.x;
    int wave = tid >> 6;
    int lane = tid & 63;

    __shared__ float qsl[64], qsh[64];
    __shared__ float scl[256];
    __shared__ float sch[512];
    __shared__ float ktile[64 * 65];
    __shared__ float redH[256], redL[256];
    __shared__ float m4[4], s4[4];

    if (tid < 64) qsl[tid] = q[((size_t)b * T + tl) * H + tid];
    else if (tid < 128) qsh[tid - 64] = q[((size_t)b * T + th) * H + (tid - 64)];
    __syncthreads();

    int nsl = tl + 1;
    int nsh = th + 1;
    const float* kbase = kp + (size_t)b * T * H;
    const float* vbase = vp + (size_t)b * T * H;
    int c0 = wave * 16;

    for (int s0 = 0; s0 < nsh; s0 += 64) {
        int tile = min(64, nsh - s0);
        for (int f = tid; f < tile * 64; f += 256) {
            int r = f >> 6, cc = f & 63;
            ktile[r * 65 + cc] = kbase[(size_t)(s0 + r) * H + cc];
        }
        __syncthreads();
        float ph = 0.f, pl = 0.f;
        if (lane < tile) {
            const float* kr = &ktile[lane * 65 + c0];
#pragma unroll
            for (int i = 0; i < 16; ++i) ph = fmaf(qsh[c0 + i], kr[i], ph);
            if (s0 + lane < nsl) {
#pragma unroll
                for (int i = 0; i < 16; ++i) pl = fmaf(qsl[c0 + i], kr[i], pl);
            }
        }
        redH[wave * 64 + lane] = ph;
        redL[wave * 64 + lane] = pl;
        __syncthreads();
        if (tid < tile) {
            sch[s0 + tid] = redH[tid] + redH[64 + tid] + redH[128 + tid] + redH[192 + tid];
            if (s0 + tid < nsl)
                scl[s0 + tid] = redL[tid] + redL[64 + tid] + redL[128 + tid] + redL[192 + tid];
        }
        __syncthreads();
    }

    float m = -INFINITY;
    for (int s = tid; s < nsh; s += 256) m = fmaxf(m, sch[s]);
#pragma unroll
    for (int off = 32; off; off >>= 1) m = fmaxf(m, __shfl_down(m, off));
    if (lane == 0) m4[wave] = m;
    __syncthreads();
    float mh = fmaxf(fmaxf(m4[0], m4[1]), fmaxf(m4[2], m4[3]));
    __syncthreads();
    m = -INFINITY;
    for (int s = tid; s < nsl; s += 256) m = fmaxf(m, scl[s]);
#pragma unroll
    for (int off = 32; off; off >>= 1) m = fmaxf(m, __shfl_down(m, off));
    if (lane == 0) m4[wave] = m;
    __syncthreads();
    float ml = fmaxf(fmaxf(m4[0], m4[1]), fmaxf(m4[2], m4[3]));

    float ls = 0.f;
    for (int s = tid; s < nsh; s += 256) {
        float e = __expf(sch[s] - mh);
        sch[s] = e;
        ls += e;
    }
#pragma unroll
    for (int off = 32; off; off >>= 1) ls += __shfl_down(ls, off);
    if (lane == 0) s4[wave] = ls;
    __syncthreads();
    float sumh = s4[0] + s4[1] + s4[2] + s4[3];
    __syncthreads();
    ls = 0.f;
    for (int s = tid; s < nsl; s += 256) {
        float e = __expf(scl[s] - ml);
        scl[s] = e;
        ls += e;
    }
#pragma unroll
    for (int off = 32; off; off >>= 1) ls += __shfl_down(ls, off);
    if (lane == 0) s4[wave] = ls;
    __syncthreads();
    float suml = s4[0] + s4[1] + s4[2] + s4[3];

    float ah = 0.f, al = 0.f;
    for (int s = wave; s < nsh; s += 4) {
        float vv = vbase[(size_t)s * H + lane];
        ah = fmaf(sch[s], vv, ah);
        if (s < nsl) al = fmaf(scl[s], vv, al);
    }
    redH[tid] = ah;
    redL[tid] = al;
    __syncthreads();

    if (tid < 64) {
        float oh = (redH[tid] + redH[64 + tid] + redH[128 + tid] + redH[192 + tid]) / sumh;
        out[((size_t)b * T + th) * H + tid] = oh;
        float ol = (redL[tid] + redL[64 + tid] + redL[128 + tid] + redL[192 + tid]) / suml;
        out[((size_t)b * T + tl) * H + tid] = ol;
    }
}

// ---------------------------------------------------------------------------
extern "C" void kernel_launch(void* const* d_in, const int* in_sizes, int n_in,
                              void* d_out, int out_size, void* d_ws, size_t ws_size,
                              hipStream_t stream) {
    const float* x        = (const float*)d_in[0];
    const int*   tok      = (const int*)d_in[1];
    const float* Wk       = (const float*)d_in[2];
    const float* Wq       = (const float*)d_in[3];
    const float* Wv       = (const float*)d_in[4];
    const float* Ek_pos   = (const float*)d_in[5];
    const float* Ev_pos   = (const float*)d_in[6];
    const float* Ek_time  = (const float*)d_in[7];
    const float* Ev_time  = (const float*)d_in[8];
    const float* Ek_pitch = (const float*)d_in[9];
    const float* Ev_pitch = (const float*)d_in[10];
    float* out = (float*)d_out;

    float* ws = (float*)d_ws;
    float* q      = ws;                        // B*T*H
    float* k      = q + B * T * H;             // B*T*H (becomes k')
    float* v      = k + B * T * H;             // B*T*H (becomes v')
    float* prop_t = v + B * T * H;             // B*T
    float* prop_p = prop_t + B * T;            // B*T
    int*   cntP   = (int*)(prop_p + B * T);    // B*129
    int*   meta   = cntP + B * 129;            // B*4
    float* tval   = (float*)(meta + B * 4);    // B*520
    int*   tcnt   = (int*)(tval + B * 520);    // B*520

    scan_kernel<<<B, 64, 0, stream>>>(tok, prop_t, prop_p, cntP, meta, tval, tcnt);
    qkv_kernel<<<3 * 256, 256, 0, stream>>>(x, Wq, Wk, Wv, q, k, v);
    relsum_kernel<<<B * T, 256, 0, stream>>>(prop_t, prop_p, cntP, meta, tval, tcnt,
                                             Ek_pos, Ev_pos, Ek_time, Ev_time,
                                             Ek_pitch, Ev_pitch, k, v);
    attn_kernel<<<B * 256, 256, 0, stream>>>(q, k, v, out);
}

// Round 6
// 137.209 us; speedup vs baseline: 1.3897x; 1.1723x over previous
//
#include <hip/hip_runtime.h>
#include <math.h>

#define B 2
#define T 512
#define C 512
#define H 64

// scale = C^-0.5 = 1/sqrt(512)
#define SCALE 0.044194173824159216f

static __device__ __forceinline__ float qnan() { return __builtin_nanf(""); }

// ---------------------------------------------------------------------------
// Kernel 1: token scans + per-batch pitch histogram + time RLE.
// One wave per batch. (unchanged from R3)
// ---------------------------------------------------------------------------
__global__ __launch_bounds__(64) void scan_kernel(const int* __restrict__ tok,
                                                  float* __restrict__ prop_t,
                                                  float* __restrict__ prop_p,
                                                  int* __restrict__ cntP,
                                                  int* __restrict__ meta,
                                                  float* __restrict__ tval,
                                                  int* __restrict__ tcnt) {
    int b = blockIdx.x;
    int lane = threadIdx.x;
    const int* tb = tok + b * T;

    __shared__ int tks[T];
    __shared__ float ptv[T];
    __shared__ float ff[T];
    __shared__ int hist[129];
    __shared__ int cnts[520];
    __shared__ int nanPc;

    for (int i = lane; i < T; i += 64) tks[i] = tb[i];
    for (int i = lane; i < 520; i += 64) cnts[i] = 0;
    for (int i = lane; i < 129; i += 64) hist[i] = 0;
    if (lane == 0) nanPc = 0;
    __syncthreads();

    const int p0 = lane * 8;
    unsigned long long lowmask = lane ? ((1ull << lane) - 1ull) : 0ull;

    // ---- time scan ----
    {
        float lsum[8];
        bool lflag[8];
        float s = 0.f;
        bool f = false;
#pragma unroll
        for (int i = 0; i < 8; ++i) {
            int tk = tks[p0 + i];
            if (tk >= 288) { s += (float)(tk - 288); f = true; }
            lsum[i] = s;
            lflag[i] = f;
        }
        float inc = s;
#pragma unroll
        for (int off = 1; off < 64; off <<= 1) {
            float o = __shfl_up(inc, off);
            if (lane >= off) inc += o;
        }
        float ex = inc - s;
        unsigned long long fmask = __ballot(f);
        bool exf = (fmask & lowmask) != 0ull;
#pragma unroll
        for (int i = 0; i < 8; ++i) {
            bool have = exf | lflag[i];
            float outv = have ? rintf((ex + lsum[i] + 1.0f) / 10.0f) : qnan();
            prop_t[b * T + p0 + i] = outv;
            ptv[p0 + i] = outv;
        }
    }

    // ---- pitch scan (copy-last-valid) ----
    {
        float lval[8];
        bool lvalid[8];
        float cv = 0.f;
        bool cvd = false;
#pragma unroll
        for (int i = 0; i < 8; ++i) {
            int tk = tks[p0 + i];
            if (tk < 256) {
                cv = (float)((tk >= 128 ? tk - 128 : tk) + 1);
                cvd = true;
            }
            lval[i] = cv;
            lvalid[i] = cvd;
        }
        unsigned long long vmask = __ballot(cvd);
        unsigned long long lower = vmask & lowmask;
        bool exvd = lower != 0ull;
        int src = 63 - __clzll(lower | 1ull);
        float exv = __shfl(cv, src);
#pragma unroll
        for (int i = 0; i < 8; ++i) {
            bool hv = exvd | lvalid[i];
            float fv = lvalid[i] ? lval[i] : exv;
            ff[p0 + i] = hv ? fv : qnan();
        }
    }
    __syncthreads();

    for (int i = lane; i < T; i += 64) {
        float v = ff[min(i + 1, T - 1)];
        prop_p[b * T + i] = v;
        if (v == v) atomicAdd(&hist[(int)v - 1], 1);
        else atomicAdd(&nanPc, 1);
    }

    // ---- time RLE ----
    int lstart[8];
    int lcnt = 0, lnan = 0;
#pragma unroll
    for (int u = 0; u < 8; ++u) {
        int i = p0 + u;
        float cur = ptv[i];
        bool val = (cur == cur);
        bool st = false;
        if (val) {
            if (i == 0) st = true;
            else {
                float pv = ptv[i - 1];
                st = !(pv == pv) || (pv != cur);
            }
        } else lnan++;
        lstart[u] = st;
        lcnt += st;
    }
    int incs = lcnt;
#pragma unroll
    for (int off = 1; off < 64; off <<= 1) {
        int o = __shfl_up(incs, off);
        if (lane >= off) incs += o;
    }
    int base = incs - lcnt;
    int Lruns = __shfl(incs, 63);
    int tn = lnan;
#pragma unroll
    for (int off = 32; off; off >>= 1) tn += __shfl_down(tn, off);
    tn = __shfl(tn, 0);

    int s2 = base;
#pragma unroll
    for (int u = 0; u < 8; ++u) {
        int i = p0 + u;
        float cur = ptv[i];
        if (lstart[u]) { tval[b * 520 + s2] = cur; s2++; }
        if (cur == cur) atomicAdd(&cnts[s2 - 1], 1);
    }
    __syncthreads();

    for (int i = lane; i < Lruns; i += 64) tcnt[b * 520 + i] = cnts[i];
    for (int i = lane; i < 129; i += 64) cntP[b * 129 + i] = hist[i];
    if (lane == 0) {
        meta[b * 4] = Lruns;
        meta[b * 4 + 1] = tn;
        meta[b * 4 + 2] = nanPc;
    }
}

// ---------------------------------------------------------------------------
// Kernel 2: q/k/v projection, matrix-split (unchanged from R5).
// ---------------------------------------------------------------------------
__global__ __launch_bounds__(256) void qkv_kernel(const float* __restrict__ x,
                                                  const float* __restrict__ Wq,
                                                  const float* __restrict__ Wk,
                                                  const float* __restrict__ Wv,
                                                  float* __restrict__ q,
                                                  float* __restrict__ k,
                                                  float* __restrict__ v) {
    int rg = blockIdx.x & 255;
    int m = blockIdx.x >> 8;
    int tid = threadIdx.x;
    int wave = tid >> 6;
    int lane = tid & 63;
    int g = lane >> 4;
    int c4 = lane & 15;

    const float* Wm = (m == 0) ? Wq : ((m == 1) ? Wk : Wv);
    float* Om = (m == 0) ? q : ((m == 1) ? k : v);

    __shared__ float xs[4 * C];
    const float4* xv4 = (const float4*)(x + (size_t)rg * 4 * C);
    float4* xs4 = (float4*)xs;
    xs4[tid] = xv4[tid];
    xs4[tid + 256] = xv4[tid + 256];
    __syncthreads();

    const float4* W4 = (const float4*)Wm;
    const float* xr = xs + wave * C;

    float4 acc = make_float4(0.f, 0.f, 0.f, 0.f);
#pragma unroll 8
    for (int u = 0; u < 128; ++u) {
        int kk = u * 4 + g;
        float4 w4 = W4[kk * 16 + c4];
        float xv = xr[kk];
        acc.x = fmaf(xv, w4.x, acc.x);
        acc.y = fmaf(xv, w4.y, acc.y);
        acc.z = fmaf(xv, w4.z, acc.z);
        acc.w = fmaf(xv, w4.w, acc.w);
    }

#pragma unroll
    for (int mask = 16; mask <= 32; mask <<= 1) {
        acc.x += __shfl_xor(acc.x, mask);
        acc.y += __shfl_xor(acc.y, mask);
        acc.z += __shfl_xor(acc.z, mask);
        acc.w += __shfl_xor(acc.w, mask);
    }

    if (g == 0) {
        float4* orow = (float4*)(Om + (size_t)(rg * 4 + wave) * H);
        orow[c4] = acc;
    }
}

// ---------------------------------------------------------------------------
// Kernel 3: relative-embedding sums via histogram/RLE entries (R3).
// ---------------------------------------------------------------------------
__global__ __launch_bounds__(256) void relsum_kernel(
    const float* __restrict__ prop_t, const float* __restrict__ prop_p,
    const int* __restrict__ cntP, const int* __restrict__ meta,
    const float* __restrict__ tval, const int* __restrict__ tcnt,
    const float* __restrict__ Ek_pos, const float* __restrict__ Ev_pos,
    const float* __restrict__ Ek_time, const float* __restrict__ Ev_time,
    const float* __restrict__ Ek_pitch, const float* __restrict__ Ev_pitch,
    float* __restrict__ k, float* __restrict__ v) {
    int b = blockIdx.x >> 9;
    int j = blockIdx.x & 511;
    int tid = threadIdx.x;
    int wave = tid >> 6;
    int c = tid & 63;

    __shared__ float tvL[520];
    __shared__ int tcL[520];
    __shared__ int cpL[129];
    __shared__ float redK[256];
    __shared__ float redV[256];

    int L = meta[b * 4];
    int nanT = meta[b * 4 + 1];
    int nanP = meta[b * 4 + 2];
    for (int i = tid; i < L; i += 256) {
        tvL[i] = tval[b * 520 + i];
        tcL[i] = tcnt[b * 520 + i];
    }
    if (tid < 129) cpL[tid] = cntP[b * 129 + tid];
    __syncthreads();

    float pjt = prop_t[b * T + j];
    float pjp = prop_p[b * T + j];

    float aK = 0.f, aV = 0.f;

    int NE = 130 + L + 1;
    for (int e = wave; e < NE; e += 4) {
        int idx, cnt;
        const float* EK;
        const float* EV;
        if (e < 130) {
            EK = Ek_pitch; EV = Ev_pitch;
            if (e == 129) { idx = 0; cnt = nanP; }
            else {
                cnt = cpL[e];
                float dv = pjp - (float)(e + 1);
                idx = (dv != dv) ? 0 : (int)dv + 128;
            }
        } else {
            EK = Ek_time; EV = Ev_time;
            int r = e - 130;
            if (r == L) { idx = 0; cnt = nanT; }
            else {
                cnt = tcL[r];
                float dt = pjt - tvL[r];
                idx = (dt != dt) ? 0 : (int)fminf(fmaxf(dt, -200.f), 200.f) + 200;
            }
        }
        if (cnt) {
            float fc = (float)cnt;
            aK = fmaf(fc, EK[idx * H + c], aK);
            aV = fmaf(fc, EV[idx * H + c], aV);
        }
    }

    int lo = max(-25, j - (T - 1));
    int hi = min(25, j);
    for (int d = lo + wave; d <= hi; d += 4) {
        aK += Ek_pos[(d + 25) * H + c];
        aV += Ev_pos[(d + 25) * H + c];
    }
    if (wave == 0) {
        float c50 = (float)max(j - 25, 0);
        float c0 = (float)max((T - 26) - j, 0);
        aK = fmaf(c50, Ek_pos[50 * H + c], aK);
        aK = fmaf(c0, Ek_pos[0 * H + c], aK);
        aV = fmaf(c50, Ev_pos[50 * H + c], aV);
        aV = fmaf(c0, Ev_pos[0 * H + c], aV);
    }

    redK[tid] = aK;
    redV[tid] = aV;
    __syncthreads();

    if (tid < 64) {
        float sK = redK[tid] + redK[64 + tid] + redK[128 + tid] + redK[192 + tid];
        float sV = redV[tid] + redV[64 + tid] + redV[128 + tid] + redV[192 + tid];
        size_t o = (size_t)blockIdx.x * H + tid;
        k[o] = SCALE * k[o] + sK;
        v[o] = v[o] + sV;
    }
}

// ---------------------------------------------------------------------------
// Kernel 4: flash-style causal attention, online softmax, wave-per-row.
// Block = 4 waves handling rows {2g, 2g+1, 510-2g, 511-2g} of batch b.
// Per 64-s tile: coop stage k (pad-65) + v (row-major) once; each wave
// privately: full 64-c dots (lane=s), wave-max, online rescale, fused PV
// (lane=c). No cross-wave reduces; 2 barriers/tile.
// ---------------------------------------------------------------------------
__global__ __launch_bounds__(256) void attn_kernel(const float* __restrict__ q,
                                                   const float* __restrict__ kp,
                                                   const float* __restrict__ vp,
                                                   float* __restrict__ out) {
    int b = blockIdx.x >> 7;
    int g = blockIdx.x & 127;
    int tid = threadIdx.x;
    int wave = tid >> 6;
    int lane = tid & 63;

    // wave -> row: w0=2g, w1=2g+1, w2=511-2g, w3=510-2g
    int t = (wave < 2) ? (2 * g + wave) : (511 - 2 * g - (wave - 2));
    int ns = t + 1;

    __shared__ float kt[64 * 65];
    __shared__ float vt[64 * 64];
    __shared__ float qs[4][64];
    __shared__ float pS[4][64];

    qs[wave][lane] = q[((size_t)b * T + t) * H + lane];  // wave-private row

    const float* kb = kp + (size_t)b * T * H;
    const float* vb = vp + (size_t)b * T * H;
    int ntiles = (512 - 2 * g + 63) / 64;  // covers max row 511-2g

    float m = -INFINITY;
    float l = 0.f;     // per-lane partial of the softmax denominator
    float acc = 0.f;   // lane holds output column c = lane

    for (int it = 0; it < ntiles; ++it) {
        int s0 = it * 64;

        // ---- cooperative stage (256 threads): 4 float4 each for k and v ----
#pragma unroll
        for (int i = 0; i < 4; ++i) {
            int f = i * 256 + tid;          // float4 index 0..1023
            int r = f >> 4;                 // tile row 0..63
            int c0 = (f & 15) << 2;         // col 0..60
            int sr = min(s0 + r, T - 1);    // clamp OOB rows (never read)
            const float4 kv = *(const float4*)(kb + (size_t)sr * H + c0);
            const float4 vv = *(const float4*)(vb + (size_t)sr * H + c0);
            kt[r * 65 + c0 + 0] = kv.x;
            kt[r * 65 + c0 + 1] = kv.y;
            kt[r * 65 + c0 + 2] = kv.z;
            kt[r * 65 + c0 + 3] = kv.w;
            *(float4*)(vt + r * 64 + c0) = vv;
        }
        __syncthreads();

        if (s0 < ns) {  // this wave still has scores in this tile
            int s = s0 + lane;
            float sc = -INFINITY;
            if (s < ns) {
                float d = 0.f;
                const float* kr = kt + lane * 65;   // (lane+c)%32 -> 2-way, free
                const float* qw = qs[wave];         // broadcast reads
#pragma unroll
                for (int c = 0; c < 64; ++c) d = fmaf(qw[c], kr[c], d);
                sc = d;
            }
            // wave max of sc
            float mt = sc;
#pragma unroll
            for (int off = 32; off; off >>= 1) mt = fmaxf(mt, __shfl_xor(mt, off));
            float mnew = fmaxf(m, mt);
            float alpha = __expf(m - mnew);         // first tile: exp(-inf)=0
            float p = (s < ns) ? __expf(sc - mnew) : 0.f;
            l = l * alpha + p;
            pS[wave][lane] = p;
            m = mnew;

            // fused PV: lane = output col
            float a = 0.f;
            int smax = min(64, ns - s0);
            for (int ss = 0; ss < smax; ++ss)
                a = fmaf(pS[wave][ss], vt[ss * 64 + lane], a);
            acc = acc * alpha + a;
        }
        __syncthreads();
    }

    // denominator = wave sum of per-lane partials
    float lt = l;
#pragma unroll
    for (int off = 32; off; off >>= 1) lt += __shfl_xor(lt, off);

    out[((size_t)b * T + t) * H + lane] = acc / lt;
}

// ---------------------------------------------------------------------------
extern "C" void kernel_launch(void* const* d_in, const int* in_sizes, int n_in,
                              void* d_out, int out_size, void* d_ws, size_t ws_size,
                              hipStream_t stream) {
    const float* x        = (const float*)d_in[0];
    const int*   tok      = (const int*)d_in[1];
    const float* Wk       = (const float*)d_in[2];
    const float* Wq       = (const float*)d_in[3];
    const float* Wv       = (const float*)d_in[4];
    const float* Ek_pos   = (const float*)d_in[5];
    const float* Ev_pos   = (const float*)d_in[6];
    const float* Ek_time  = (const float*)d_in[7];
    const float* Ev_time  = (const float*)d_in[8];
    const float* Ek_pitch = (const float*)d_in[9];
    const float* Ev_pitch = (const float*)d_in[10];
    float* out = (float*)d_out;

    float* ws = (float*)d_ws;
    float* q      = ws;                        // B*T*H
    float* k      = q + B * T * H;             // B*T*H (becomes k')
    float* v      = k + B * T * H;             // B*T*H (becomes v')
    float* prop_t = v + B * T * H;             // B*T
    float* prop_p = prop_t + B * T;            // B*T
    int*   cntP   = (int*)(prop_p + B * T);    // B*129
    int*   meta   = cntP + B * 129;            // B*4
    float* tval   = (float*)(meta + B * 4);    // B*520
    int*   tcnt   = (int*)(tval + B * 520);    // B*520

    scan_kernel<<<B, 64, 0, stream>>>(tok, prop_t, prop_p, cntP, meta, tval, tcnt);
    qkv_kernel<<<3 * 256, 256, 0, stream>>>(x, Wq, Wk, Wv, q, k, v);
    relsum_kernel<<<B * T, 256, 0, stream>>>(prop_t, prop_p, cntP, meta, tval, tcnt,
                                             Ek_pos, Ev_pos, Ek_time, Ev_time,
                                             Ek_pitch, Ev_pitch, k, v);
    attn_kernel<<<B * 128, 256, 0, stream>>>(q, k, v, out);
}

// Round 7
// 131.001 us; speedup vs baseline: 1.4555x; 1.0474x over previous
//
#include <hip/hip_runtime.h>
#include <math.h>

#define B 2
#define T 512
#define C 512
#define H 64

// scale = C^-0.5 = 1/sqrt(512)
#define SCALE 0.044194173824159216f

static __device__ __forceinline__ float qnan() { return __builtin_nanf(""); }

// ---------------------------------------------------------------------------
// Kernel 1: token scans + per-batch pitch histogram + time RLE.
// One wave per batch. (unchanged from R3)
// ---------------------------------------------------------------------------
__global__ __launch_bounds__(64) void scan_kernel(const int* __restrict__ tok,
                                                  float* __restrict__ prop_t,
                                                  float* __restrict__ prop_p,
                                                  int* __restrict__ cntP,
                                                  int* __restrict__ meta,
                                                  float* __restrict__ tval,
                                                  int* __restrict__ tcnt) {
    int b = blockIdx.x;
    int lane = threadIdx.x;
    const int* tb = tok + b * T;

    __shared__ int tks[T];
    __shared__ float ptv[T];
    __shared__ float ff[T];
    __shared__ int hist[129];
    __shared__ int cnts[520];
    __shared__ int nanPc;

    for (int i = lane; i < T; i += 64) tks[i] = tb[i];
    for (int i = lane; i < 520; i += 64) cnts[i] = 0;
    for (int i = lane; i < 129; i += 64) hist[i] = 0;
    if (lane == 0) nanPc = 0;
    __syncthreads();

    const int p0 = lane * 8;
    unsigned long long lowmask = lane ? ((1ull << lane) - 1ull) : 0ull;

    // ---- time scan ----
    {
        float lsum[8];
        bool lflag[8];
        float s = 0.f;
        bool f = false;
#pragma unroll
        for (int i = 0; i < 8; ++i) {
            int tk = tks[p0 + i];
            if (tk >= 288) { s += (float)(tk - 288); f = true; }
            lsum[i] = s;
            lflag[i] = f;
        }
        float inc = s;
#pragma unroll
        for (int off = 1; off < 64; off <<= 1) {
            float o = __shfl_up(inc, off);
            if (lane >= off) inc += o;
        }
        float ex = inc - s;
        unsigned long long fmask = __ballot(f);
        bool exf = (fmask & lowmask) != 0ull;
#pragma unroll
        for (int i = 0; i < 8; ++i) {
            bool have = exf | lflag[i];
            float outv = have ? rintf((ex + lsum[i] + 1.0f) / 10.0f) : qnan();
            prop_t[b * T + p0 + i] = outv;
            ptv[p0 + i] = outv;
        }
    }

    // ---- pitch scan (copy-last-valid) ----
    {
        float lval[8];
        bool lvalid[8];
        float cv = 0.f;
        bool cvd = false;
#pragma unroll
        for (int i = 0; i < 8; ++i) {
            int tk = tks[p0 + i];
            if (tk < 256) {
                cv = (float)((tk >= 128 ? tk - 128 : tk) + 1);
                cvd = true;
            }
            lval[i] = cv;
            lvalid[i] = cvd;
        }
        unsigned long long vmask = __ballot(cvd);
        unsigned long long lower = vmask & lowmask;
        bool exvd = lower != 0ull;
        int src = 63 - __clzll(lower | 1ull);
        float exv = __shfl(cv, src);
#pragma unroll
        for (int i = 0; i < 8; ++i) {
            bool hv = exvd | lvalid[i];
            float fv = lvalid[i] ? lval[i] : exv;
            ff[p0 + i] = hv ? fv : qnan();
        }
    }
    __syncthreads();

    for (int i = lane; i < T; i += 64) {
        float v = ff[min(i + 1, T - 1)];
        prop_p[b * T + i] = v;
        if (v == v) atomicAdd(&hist[(int)v - 1], 1);
        else atomicAdd(&nanPc, 1);
    }

    // ---- time RLE ----
    int lstart[8];
    int lcnt = 0, lnan = 0;
#pragma unroll
    for (int u = 0; u < 8; ++u) {
        int i = p0 + u;
        float cur = ptv[i];
        bool val = (cur == cur);
        bool st = false;
        if (val) {
            if (i == 0) st = true;
            else {
                float pv = ptv[i - 1];
                st = !(pv == pv) || (pv != cur);
            }
        } else lnan++;
        lstart[u] = st;
        lcnt += st;
    }
    int incs = lcnt;
#pragma unroll
    for (int off = 1; off < 64; off <<= 1) {
        int o = __shfl_up(incs, off);
        if (lane >= off) incs += o;
    }
    int base = incs - lcnt;
    int Lruns = __shfl(incs, 63);
    int tn = lnan;
#pragma unroll
    for (int off = 32; off; off >>= 1) tn += __shfl_down(tn, off);
    tn = __shfl(tn, 0);

    int s2 = base;
#pragma unroll
    for (int u = 0; u < 8; ++u) {
        int i = p0 + u;
        float cur = ptv[i];
        if (lstart[u]) { tval[b * 520 + s2] = cur; s2++; }
        if (cur == cur) atomicAdd(&cnts[s2 - 1], 1);
    }
    __syncthreads();

    for (int i = lane; i < Lruns; i += 64) tcnt[b * 520 + i] = cnts[i];
    for (int i = lane; i < 129; i += 64) cntP[b * 129 + i] = hist[i];
    if (lane == 0) {
        meta[b * 4] = Lruns;
        meta[b * 4 + 1] = tn;
        meta[b * 4 + 2] = nanPc;
    }
}

// ---------------------------------------------------------------------------
// Kernel 2: q/k/v projection v3. Block = (16-row group, matrix m), 256 thr.
// Wave w handles rows rg*16 + 4w .. +3 with 4 independent float4 accums;
// lane = (g = kk%4, c4 = col quad). W streamed ONCE per wave (not per row):
// L2 W-traffic 4x lower than R5; 16 indep FMA chains/thread.
// ---------------------------------------------------------------------------
__global__ __launch_bounds__(256) void qkv_kernel(const float* __restrict__ x,
                                                  const float* __restrict__ Wq,
                                                  const float* __restrict__ Wk,
                                                  const float* __restrict__ Wv,
                                                  float* __restrict__ q,
                                                  float* __restrict__ k,
                                                  float* __restrict__ v) {
    int rg = blockIdx.x & 63;            // 16-row group (64 groups)
    int m = blockIdx.x >> 6;             // 0=q, 1=k, 2=v
    int tid = threadIdx.x;
    int wave = tid >> 6;
    int lane = tid & 63;
    int g = lane >> 4;                   // kk % 4 group
    int c4 = lane & 15;                  // float4 column index

    const float* Wm = (m == 0) ? Wq : ((m == 1) ? Wk : Wv);
    float* Om = (m == 0) ? q : ((m == 1) ? k : v);

    __shared__ float xs[16 * C];         // 32 KB
    const float4* xv4 = (const float4*)(x + (size_t)rg * 16 * C);
    float4* xs4 = (float4*)xs;
#pragma unroll
    for (int i = 0; i < 8; ++i) xs4[tid + 256 * i] = xv4[tid + 256 * i];
    __syncthreads();

    const float4* W4 = (const float4*)Wm;         // [512][16]
    const float* xr = xs + (wave * 4) * C;        // 4 rows for this wave

    float4 a0 = make_float4(0.f, 0.f, 0.f, 0.f);
    float4 a1 = a0, a2 = a0, a3 = a0;
#pragma unroll 4
    for (int u = 0; u < 128; ++u) {
        int kk = u * 4 + g;
        float4 w4 = W4[kk * 16 + c4];
        float x0 = xr[kk];
        float x1 = xr[C + kk];
        float x2 = xr[2 * C + kk];
        float x3 = xr[3 * C + kk];
        a0.x = fmaf(x0, w4.x, a0.x); a0.y = fmaf(x0, w4.y, a0.y);
        a0.z = fmaf(x0, w4.z, a0.z); a0.w = fmaf(x0, w4.w, a0.w);
        a1.x = fmaf(x1, w4.x, a1.x); a1.y = fmaf(x1, w4.y, a1.y);
        a1.z = fmaf(x1, w4.z, a1.z); a1.w = fmaf(x1, w4.w, a1.w);
        a2.x = fmaf(x2, w4.x, a2.x); a2.y = fmaf(x2, w4.y, a2.y);
        a2.z = fmaf(x2, w4.z, a2.z); a2.w = fmaf(x2, w4.w, a2.w);
        a3.x = fmaf(x3, w4.x, a3.x); a3.y = fmaf(x3, w4.y, a3.y);
        a3.z = fmaf(x3, w4.z, a3.z); a3.w = fmaf(x3, w4.w, a3.w);
    }

    // fold the 4 kk-groups (lane bits 4,5)
#pragma unroll
    for (int mask = 16; mask <= 32; mask <<= 1) {
        a0.x += __shfl_xor(a0.x, mask); a0.y += __shfl_xor(a0.y, mask);
        a0.z += __shfl_xor(a0.z, mask); a0.w += __shfl_xor(a0.w, mask);
        a1.x += __shfl_xor(a1.x, mask); a1.y += __shfl_xor(a1.y, mask);
        a1.z += __shfl_xor(a1.z, mask); a1.w += __shfl_xor(a1.w, mask);
        a2.x += __shfl_xor(a2.x, mask); a2.y += __shfl_xor(a2.y, mask);
        a2.z += __shfl_xor(a2.z, mask); a2.w += __shfl_xor(a2.w, mask);
        a3.x += __shfl_xor(a3.x, mask); a3.y += __shfl_xor(a3.y, mask);
        a3.z += __shfl_xor(a3.z, mask); a3.w += __shfl_xor(a3.w, mask);
    }

    if (g == 0) {
        size_t row0 = (size_t)(rg * 16 + wave * 4);
        ((float4*)(Om + (row0 + 0) * H))[c4] = a0;
        ((float4*)(Om + (row0 + 1) * H))[c4] = a1;
        ((float4*)(Om + (row0 + 2) * H))[c4] = a2;
        ((float4*)(Om + (row0 + 3) * H))[c4] = a3;
    }
}

// ---------------------------------------------------------------------------
// Kernel 3: relative-embedding sums v2. Fixed-trip unrollable pitch loop
// (idx = ipjp+127-e, no clip needed), dynamic time loop (unroll 2), NaN
// terms as single scalar FMAs, pos window unchanged.
// ---------------------------------------------------------------------------
__global__ __launch_bounds__(256) void relsum_kernel(
    const float* __restrict__ prop_t, const float* __restrict__ prop_p,
    const int* __restrict__ cntP, const int* __restrict__ meta,
    const float* __restrict__ tval, const int* __restrict__ tcnt,
    const float* __restrict__ Ek_pos, const float* __restrict__ Ev_pos,
    const float* __restrict__ Ek_time, const float* __restrict__ Ev_time,
    const float* __restrict__ Ek_pitch, const float* __restrict__ Ev_pitch,
    float* __restrict__ k, float* __restrict__ v) {
    int b = blockIdx.x >> 9;
    int j = blockIdx.x & 511;
    int tid = threadIdx.x;
    int wave = tid >> 6;
    int c = tid & 63;

    __shared__ float tvL[520];
    __shared__ int tcL[520];
    __shared__ int cpL[132];
    __shared__ float redK[256];
    __shared__ float redV[256];

    int L = meta[b * 4];
    int nanT = meta[b * 4 + 1];
    int nanP = meta[b * 4 + 2];
    for (int i = tid; i < L; i += 256) {
        tvL[i] = tval[b * 520 + i];
        tcL[i] = tcnt[b * 520 + i];
    }
    if (tid < 129) cpL[tid] = cntP[b * 129 + tid];
    else if (tid < 132) cpL[tid] = 0;   // pad so e=129..131 read zero
    __syncthreads();

    float pjt = prop_t[b * T + j];
    float pjp = prop_p[b * T + j];
    bool pvalid = (pjp == pjp);
    int ipjp = pvalid ? (int)pjp : 0;

    float aK = 0.f, aV = 0.f;

    // ---- pitch: 129 bins, idx = ipjp+127-e (exact, in [0,255]); NaN -> 0 ----
#pragma unroll 3
    for (int i = 0; i < 33; ++i) {
        int e = wave + i * 4;            // 0..131, cpL padded with 0
        int cnt = cpL[e];
        if (cnt) {
            int idx = pvalid ? (ipjp + 127 - e) : 0;
            float fc = (float)cnt;
            aK = fmaf(fc, Ek_pitch[idx * H + c], aK);
            aV = fmaf(fc, Ev_pitch[idx * H + c], aV);
        }
    }
    if (wave == 3 && nanP) {
        float fc = (float)nanP;
        aK = fmaf(fc, Ek_pitch[c], aK);
        aV = fmaf(fc, Ev_pitch[c], aV);
    }

    // ---- time runs ----
#pragma unroll 2
    for (int r = wave; r < L; r += 4) {
        int cnt = tcL[r];
        float dt = pjt - tvL[r];
        int idx = (dt != dt) ? 0 : (int)fminf(fmaxf(dt, -200.f), 200.f) + 200;
        float fc = (float)cnt;
        aK = fmaf(fc, Ek_time[idx * H + c], aK);
        aV = fmaf(fc, Ev_time[idx * H + c], aV);
    }
    if (wave == 1 && nanT) {
        float fc = (float)nanT;
        aK = fmaf(fc, Ek_time[c], aK);
        aV = fmaf(fc, Ev_time[c], aV);
    }

    // ---- pos window + edge multiplicities ----
    int lo = max(-25, j - (T - 1));
    int hi = min(25, j);
    for (int d = lo + wave; d <= hi; d += 4) {
        aK += Ek_pos[(d + 25) * H + c];
        aV += Ev_pos[(d + 25) * H + c];
    }
    if (wave == 0) {
        float c50 = (float)max(j - 25, 0);
        float c0 = (float)max((T - 26) - j, 0);
        aK = fmaf(c50, Ek_pos[50 * H + c], aK);
        aK = fmaf(c0, Ek_pos[0 * H + c], aK);
        aV = fmaf(c50, Ev_pos[50 * H + c], aV);
        aV = fmaf(c0, Ev_pos[0 * H + c], aV);
    }

    redK[tid] = aK;
    redV[tid] = aV;
    __syncthreads();

    if (tid < 64) {
        float sK = redK[tid] + redK[64 + tid] + redK[128 + tid] + redK[192 + tid];
        float sV = redV[tid] + redV[64 + tid] + redV[128 + tid] + redV[192 + tid];
        size_t o = (size_t)blockIdx.x * H + tid;
        k[o] = SCALE * k[o] + sK;
        v[o] = v[o] + sV;
    }
}

// ---------------------------------------------------------------------------
// Kernel 4: flash-style causal attention (R6 structure) with 4-way split
// accumulator chains in the score dot and PV loops (4x shorter dependence
// chains; occupancy unchanged).
// ---------------------------------------------------------------------------
__global__ __launch_bounds__(256) void attn_kernel(const float* __restrict__ q,
                                                   const float* __restrict__ kp,
                                                   const float* __restrict__ vp,
                                                   float* __restrict__ out) {
    int b = blockIdx.x >> 7;
    int g = blockIdx.x & 127;
    int tid = threadIdx.x;
    int wave = tid >> 6;
    int lane = tid & 63;

    int t = (wave < 2) ? (2 * g + wave) : (511 - 2 * g - (wave - 2));
    int ns = t + 1;

    __shared__ float kt[64 * 65];
    __shared__ float vt[64 * 64];
    __shared__ float qs[4][64];
    __shared__ float pS[4][64];

    qs[wave][lane] = q[((size_t)b * T + t) * H + lane];

    const float* kb = kp + (size_t)b * T * H;
    const float* vb = vp + (size_t)b * T * H;
    int ntiles = (512 - 2 * g + 63) / 64;

    float m = -INFINITY;
    float l = 0.f;
    float acc = 0.f;

    for (int it = 0; it < ntiles; ++it) {
        int s0 = it * 64;

#pragma unroll
        for (int i = 0; i < 4; ++i) {
            int f = i * 256 + tid;
            int r = f >> 4;
            int c0 = (f & 15) << 2;
            int sr = min(s0 + r, T - 1);
            const float4 kv = *(const float4*)(kb + (size_t)sr * H + c0);
            const float4 vv = *(const float4*)(vb + (size_t)sr * H + c0);
            kt[r * 65 + c0 + 0] = kv.x;
            kt[r * 65 + c0 + 1] = kv.y;
            kt[r * 65 + c0 + 2] = kv.z;
            kt[r * 65 + c0 + 3] = kv.w;
            *(float4*)(vt + r * 64 + c0) = vv;
        }
        __syncthreads();

        if (s0 < ns) {
            int s = s0 + lane;
            float sc = -INFINITY;
            if (s < ns) {
                const float* kr = kt + lane * 65;
                const float* qw = qs[wave];
                float d0 = 0.f, d1 = 0.f, d2 = 0.f, d3 = 0.f;
#pragma unroll
                for (int c = 0; c < 64; c += 4) {
                    d0 = fmaf(qw[c + 0], kr[c + 0], d0);
                    d1 = fmaf(qw[c + 1], kr[c + 1], d1);
                    d2 = fmaf(qw[c + 2], kr[c + 2], d2);
                    d3 = fmaf(qw[c + 3], kr[c + 3], d3);
                }
                sc = (d0 + d1) + (d2 + d3);
            }
            float mt = sc;
#pragma unroll
            for (int off = 32; off; off >>= 1) mt = fmaxf(mt, __shfl_xor(mt, off));
            float mnew = fmaxf(m, mt);
            float alpha = __expf(m - mnew);
            float p = (s < ns) ? __expf(sc - mnew) : 0.f;
            l = l * alpha + p;
            pS[wave][lane] = p;
            m = mnew;

            float a0 = 0.f, a1 = 0.f, a2 = 0.f, a3 = 0.f;
            int smax = min(64, ns - s0);
            const float* pw = pS[wave];
            int ss = 0;
            for (; ss + 4 <= smax; ss += 4) {
                a0 = fmaf(pw[ss + 0], vt[(ss + 0) * 64 + lane], a0);
                a1 = fmaf(pw[ss + 1], vt[(ss + 1) * 64 + lane], a1);
                a2 = fmaf(pw[ss + 2], vt[(ss + 2) * 64 + lane], a2);
                a3 = fmaf(pw[ss + 3], vt[(ss + 3) * 64 + lane], a3);
            }
            for (; ss < smax; ++ss)
                a0 = fmaf(pw[ss], vt[ss * 64 + lane], a0);
            acc = acc * alpha + ((a0 + a1) + (a2 + a3));
        }
        __syncthreads();
    }

    float lt = l;
#pragma unroll
    for (int off = 32; off; off >>= 1) lt += __shfl_xor(lt, off);

    out[((size_t)b * T + t) * H + lane] = acc / lt;
}

// ---------------------------------------------------------------------------
extern "C" void kernel_launch(void* const* d_in, const int* in_sizes, int n_in,
                              void* d_out, int out_size, void* d_ws, size_t ws_size,
                              hipStream_t stream) {
    const float* x        = (const float*)d_in[0];
    const int*   tok      = (const int*)d_in[1];
    const float* Wk       = (const float*)d_in[2];
    const float* Wq       = (const float*)d_in[3];
    const float* Wv       = (const float*)d_in[4];
    const float* Ek_pos   = (const float*)d_in[5];
    const float* Ev_pos   = (const float*)d_in[6];
    const float* Ek_time  = (const float*)d_in[7];
    const float* Ev_time  = (const float*)d_in[8];
    const float* Ek_pitch = (const float*)d_in[9];
    const float* Ev_pitch = (const float*)d_in[10];
    float* out = (float*)d_out;

    float* ws = (float*)d_ws;
    float* q      = ws;                        // B*T*H
    float* k      = q + B * T * H;             // B*T*H (becomes k')
    float* v      = k + B * T * H;             // B*T*H (becomes v')
    float* prop_t = v + B * T * H;             // B*T
    float* prop_p = prop_t + B * T;            // B*T
    int*   cntP   = (int*)(prop_p + B * T);    // B*129
    int*   meta   = cntP + B * 129;            // B*4
    float* tval   = (float*)(meta + B * 4);    // B*520
    int*   tcnt   = (int*)(tval + B * 520);    // B*520

    scan_kernel<<<B, 64, 0, stream>>>(tok, prop_t, prop_p, cntP, meta, tval, tcnt);
    qkv_kernel<<<3 * 64, 256, 0, stream>>>(x, Wq, Wk, Wv, q, k, v);
    relsum_kernel<<<B * T, 256, 0, stream>>>(prop_t, prop_p, cntP, meta, tval, tcnt,
                                             Ek_pos, Ev_pos, Ek_time, Ev_time,
                                             Ek_pitch, Ev_pitch, k, v);
    attn_kernel<<<B * 128, 256, 0, stream>>>(q, k, v, out);
}